// Round 10
// baseline (904.739 us; speedup 1.0000x reference)
//
#include <hip/hip_runtime.h>
#include <hip/hip_bf16.h>

#define NN 1024
#define BB 256
#define NSWEEP 10   // born + 10 bisections + finalize decision; bf16 term ~8 << 25.76
#define GRP 8       // blocks per sample-group

typedef __attribute__((ext_vector_type(8))) short short8;
typedef __attribute__((ext_vector_type(4))) float f32x4;
typedef __attribute__((ext_vector_type(4))) unsigned short u16x4;
typedef __attribute__((ext_vector_type(4))) int i32x4;

#define MFMA(a,b,c) __builtin_amdgcn_mfma_f32_16x16x32_bf16(a,b,c,0,0,0)

__device__ __forceinline__ unsigned short f2bf(float f) {
    union { float f; unsigned int i; } c; c.f = f;
    unsigned int x = c.i;
    return (unsigned short)((x + 0x7fffu + ((x >> 16) & 1u)) >> 16);
}
__device__ __forceinline__ float bf2f(unsigned short u) {
    union { unsigned int i; float f; } c; c.i = ((unsigned int)u) << 16; return c.f;
}
__device__ __forceinline__ float frcp(float x) { return __builtin_amdgcn_rcpf(x); }

// ---- coherent-point helpers (MALL; XCD L2s not cross-coherent) ----
__device__ __forceinline__ void st_u16_sc(unsigned short* p, unsigned short v) {
    asm volatile("global_store_short %0, %1, off sc0 sc1" :: "v"(p), "v"((unsigned)v) : "memory");
}
__device__ __forceinline__ void st_f32_sc(float* p, float v) {
    asm volatile("global_store_dword %0, %1, off sc0 sc1" :: "v"(p), "v"(v) : "memory");
}
__device__ __forceinline__ float ld_f32_sc(const float* p) {
    float v;
    asm volatile("global_load_dword %0, %1, off sc0 sc1\n\ts_waitcnt vmcnt(0)"
                 : "=v"(v) : "v"(p) : "memory");
    return v;
}
__device__ __forceinline__ void ld2_f32_sc(const float* p0, const float* p1, float& a, float& b) {
    asm volatile("global_load_dword %0, %2, off sc0 sc1\n\t"
                 "global_load_dword %1, %3, off sc0 sc1\n\t"
                 "s_waitcnt vmcnt(0)"
                 : "=&v"(a), "=&v"(b) : "v"(p0), "v"(p1) : "memory");
}
__device__ __forceinline__ void ld2k_sc(const char* p, i32x4* r) {
    asm volatile(
        "global_load_dwordx4 %0, %2, off sc0 sc1\n\t"
        "global_load_dwordx4 %1, %2, off offset:1024 sc0 sc1\n\t"
        "s_waitcnt vmcnt(0)"
        : "=&v"(r[0]), "=&v"(r[1]) : "v"(p) : "memory");
}

// ---- split group barrier: monotonic count lines, arrive/wait decoupled ----
__device__ __forceinline__ void bar_arrive(int* line) {
    asm volatile("s_waitcnt vmcnt(0)" ::: "memory");
    __syncthreads();
    if (threadIdx.x == 0)
        __hip_atomic_fetch_add(line, 1, __ATOMIC_RELAXED, __HIP_MEMORY_SCOPE_AGENT);
}
__device__ __forceinline__ void bar_wait(const int* line, int target) {
    if (threadIdx.x == 0) {
        int g;
        for (;;) {
            asm volatile("global_load_dword %0, %1, off sc0 sc1\n\ts_waitcnt vmcnt(0)"
                         : "=v"(g) : "v"(line) : "memory");
            if (g >= target) break;
            __builtin_amdgcn_s_sleep(1);
        }
    }
    __syncthreads();
}

// ---------------- precompute: Cact/Cinh (bf16) + w (col-sums) ----------------
__global__ __launch_bounds__(256) void prep_kernel(
    const float* __restrict__ k1, const float* __restrict__ k1n, const float* __restrict__ k2,
    const float* __restrict__ k3, const float* __restrict__ k3n, const float* __restrict__ k4,
    const float* __restrict__ TA0, const float* __restrict__ TI0, const float* __restrict__ Ci0,
    const float* __restrict__ masks, const float* __restrict__ E0p,
    unsigned short* __restrict__ Cact, unsigned short* __restrict__ Cinh, float* __restrict__ w)
{
    int bid = blockIdx.x;
    int l = bid >> 6;
    int rc = bid & 63;
    int t = threadIdx.x;
    float E0 = E0p[0];
    size_t base = (size_t)l * NN * NN + (size_t)rc * 16 * NN;
    int col0 = t * 4;
    float wsum0 = 0.f, wsum1 = 0.f, wsum2 = 0.f, wsum3 = 0.f;
    for (int r = 0; r < 16; ++r) {
        size_t idx = base + (size_t)r * NN + col0;
        f32x4 m  = *(const f32x4*)(masks + idx);
        f32x4 a1 = *(const f32x4*)(k1 + idx);
        f32x4 b1 = *(const f32x4*)(k1n + idx);
        f32x4 a2 = *(const f32x4*)(k2 + idx);
        f32x4 ta = *(const f32x4*)(TA0 + idx);
        f32x4 a3 = *(const f32x4*)(k3 + idx);
        f32x4 b3 = *(const f32x4*)(k3n + idx);
        f32x4 a4 = *(const f32x4*)(k4 + idx);
        f32x4 ti = *(const f32x4*)(TI0 + idx);
        f32x4 ci = *(const f32x4*)(Ci0 + idx);
        u16x4 oa, oi;
        float ws[4];
        #pragma unroll
        for (int j = 0; j < 4; ++j) {
            float ka = a1[j] * ta[j] * frcp(b1[j] + a2[j]);
            float ki = a3[j] * ti[j] * frcp(b3[j] + a4[j]);
            bool act = m[j] > 0.f, inh = m[j] < 0.f;
            oa[j] = f2bf(act ? a2[j] * ka * E0 : 0.f);
            oi[j] = f2bf(inh ? ci[j] : 0.f);
            ws[j] = (act ? ka : 0.f) + (inh ? ki : 0.f);
        }
        wsum0 += ws[0]; wsum1 += ws[1]; wsum2 += ws[2]; wsum3 += ws[3];
        *(u16x4*)(Cact + idx) = oa;
        *(u16x4*)(Cinh + idx) = oi;
    }
    atomicAdd(&w[l * NN + col0 + 0], wsum0);
    atomicAdd(&w[l * NN + col0 + 1], wsum1);
    atomicAdd(&w[l * NN + col0 + 2], wsum2);
    atomicAdd(&w[l * NN + col0 + 3], wsum3);
}

__global__ __launch_bounds__(256) void x0_kernel(const float* __restrict__ in,
                                                 unsigned short* __restrict__ o,
                                                 const float* __restrict__ w,
                                                 unsigned short* __restrict__ pw1b)
{
    int i = (blockIdx.x * 256 + threadIdx.x) * 4;
    f32x4 v = *(const f32x4*)(in + i);
    u16x4 r;
    #pragma unroll
    for (int j = 0; j < 4; ++j) r[j] = f2bf(v[j]);
    *(u16x4*)(o + i) = r;
    if (blockIdx.x < 4) {
        int p = blockIdx.x * 256 + threadIdx.x;
        pw1b[p] = f2bf(w[NN + p]);
    }
}

// ---------------- cooperative solve: 64 fat blocks, atomic-free D ----------------
// 64 blocks x 1024 threads (16 waves). Block tile: 32 samples (bt, 8 groups) x 128 outs
// (ot = bid&7 -> one ot per XCD, B-slices 1MB L2-resident). Half-split pipeline (H0/H1).
// dcp partials stored per (parity, ot, row) — no atomics, no resets; UPDATE gathers.
__global__ __launch_bounds__(1024) void solve_kernel(
    const float* __restrict__ inputs,
    const unsigned short* __restrict__ X0,
    const unsigned short* __restrict__ Cact,
    const unsigned short* __restrict__ Cinh,
    unsigned short* __restrict__ U0b, unsigned short* __restrict__ V0b,
    unsigned short* __restrict__ X2,
    const float* __restrict__ w,
    float* __restrict__ DpA, float* __restrict__ DpB, float* __restrict__ DpC,
    int* __restrict__ bar, const unsigned short* __restrict__ pw1b,
    const float* __restrict__ k6, const float* __restrict__ kdI,
    const float* __restrict__ kdT, float* __restrict__ out)
{
    __shared__ unsigned short bufs[2][16][1024];      // 64KB: per-half X tile (XOR-swizzled)
    __shared__ float redf[4096];                      // 16KB: K-split partials [oc8][8][64]
    __shared__ float dsum[8][16];                     // per-oc dcp partials
    __shared__ float gsum[8][16];                     // UPDATE gather scratch
    __shared__ float lo_s[32], hi_s[32], cp_s[32], dcp0_s[32];
    __shared__ float w_s[4][128], kdT_s[4][128], kdI_s[4][128], k6_s[4][128];

    const int bid = blockIdx.x;
    const int ot = bid & 7;          // out-tile (128 outs); same-ot -> same XCD (L2-local B)
    const int bt = bid >> 3;         // sample group (8 groups x 8 blocks)
    const int b0 = bt * 32, o0 = ot * 128;
    const int tid = threadIdx.x;
    const int wid = tid >> 6, lane = tid & 63;
    const int r16 = lane & 15, g4 = lane >> 4;
    // sweep-GEMM mapping: 8 out-subtiles (oc) x 2-way K-split (kw, K=512 each)
    const int oc = wid & 7, kw = wid >> 3;
    const int brow = o0 + oc * 16 + r16;
    // phase-0 mapping: 2 sample-subtiles x 8 out-subtiles, full K per wave
    const int oc0 = wid & 7, bh0 = wid >> 3;
    const int arow0 = b0 + bh0 * 16 + r16;
    const int brow0 = o0 + oc0 * 16 + r16;

    int* L_x0 = bar + bt * 256;       // X2-ready, half 0
    int* L_x1 = L_x0 + 64;            // X2-ready, half 1
    int* L_d0 = L_x0 + 128;           // D-ready, half 0 (also phase0->sweep0 gate)
    int* L_d1 = L_x0 + 192;           // D-ready, half 1

    // ---- init LDS params (128 outs x 4 layers) ----
    if (tid < 512) {
        int l = tid >> 7, c = tid & 127;
        w_s[l][c]   = w[l * NN + o0 + c];
        kdT_s[l][c] = kdT[l * NN + o0 + c];
        kdI_s[l][c] = kdI[l * NN + o0 + c];
        k6_s[l][c]  = k6[l * NN + o0 + c];
    }
    {   // dcp0 = w0 . x0  (fp32 exact)
        int row = tid >> 5, seg = tid & 31;
        const float* xr = inputs + (size_t)(b0 + row) * NN + seg * 32;
        const float* wr = w + seg * 32;
        float p = 0.f;
        #pragma unroll
        for (int kk = 0; kk < 32; ++kk) p += wr[kk] * xr[kk];
        p += __shfl_xor(p, 1); p += __shfl_xor(p, 2); p += __shfl_xor(p, 4);
        p += __shfl_xor(p, 8); p += __shfl_xor(p, 16);
        if (seg == 0) dcp0_s[row] = p;
    }
    __syncthreads();

    // ---- phase 0: U' = (Cact0@X0)/kdT0, V' = (k60/kdI0)*(Cinh0@X0)/kdT0 (bf16, sc) ----
    {
        f32x4 aa = {0.f,0.f,0.f,0.f}, ai = {0.f,0.f,0.f,0.f};
        const short8* pa = (const short8*)(X0 + (size_t)arow0 * NN) + g4;
        const short8* pb = (const short8*)(Cact + (size_t)brow0 * NN) + g4;
        const short8* pc = (const short8*)(Cinh + (size_t)brow0 * NN) + g4;
        #pragma unroll 8
        for (int s = 0; s < 32; ++s) {
            short8 av = pa[s * 4];
            aa = MFMA(av, pb[s * 4], aa);
            ai = MFMA(av, pc[s * 4], ai);
        }
        int ol = oc0 * 16 + r16;
        float ia = frcp(kdT_s[0][ol]);
        float cc = k6_s[0][ol] * frcp(kdI_s[0][ol]);
        #pragma unroll
        for (int r = 0; r < 4; ++r) {
            size_t idx = (size_t)(b0 + bh0*16 + g4*4 + r) * NN + o0 + ol;
            st_u16_sc(&U0b[idx], f2bf(aa[r] * ia));
            st_u16_sc(&V0b[idx], f2bf(ai[r] * cc * ia));
        }
    }
    // arrive on both D lines (phase0 -> sweep0 gate)
    asm volatile("s_waitcnt vmcnt(0)" ::: "memory");
    __syncthreads();
    if (tid == 0) {
        __hip_atomic_fetch_add(L_d0, 1, __ATOMIC_RELAXED, __HIP_MEMORY_SCOPE_AGENT);
        __hip_atomic_fetch_add(L_d1, 1, __ATOMIC_RELAXED, __HIP_MEMORY_SCOPE_AGENT);
    }

    // ---- lambdas ----
    // gather partials (parity t-1) + bisection decision; t==NSWEEP+1 => final decision
    auto UPDATE = [&](int h, int t) {
        const int prevsig = (t - 1) & 1;
        if (tid < 128) {
            int o = tid >> 4, i = tid & 15;
            int row = b0 + h*16 + i;
            float vb, vc;
            ld2_f32_sc(&DpB[(prevsig*8 + o)*BB + row], &DpC[(prevsig*8 + o)*BB + row], vb, vc);
            gsum[o][i] = vb + vc;
        }
        __syncthreads();
        if (tid < 16) {
            int i = h*16 + tid;
            float S = ld_f32_sc(&DpA[prevsig*BB + b0 + i]);
            #pragma unroll
            for (int o = 0; o < 8; ++o) S += gsum[o][tid];
            float G = 1.f + dcp0_s[i] + S;
            float lo, hi;
            if (t == 1) { lo = 1.f; hi = G; }
            else {
                lo = lo_s[i]; hi = hi_s[i];
                float mid = cp_s[i];
                if (G > mid) lo = mid; else hi = mid;
            }
            lo_s[i] = lo; hi_s[i] = hi;
            cp_s[i] = 0.5f * (lo + hi);
        }
    };
    auto PHASE_A = [&](int h, char* xb, bool born_, int sig) {
        int lr = wid;                              // one wave per sample row
        int row = b0 + h*16 + lr;
        const unsigned short* Ur = U0b + (size_t)row * NN + lane*16;
        const unsigned short* Vr = V0b + (size_t)row * NN + lane*16;
        const unsigned short* Wr = pw1b + lane*16;
        float cp = born_ ? 1.f : cp_s[h*16 + lr];
        float icp = frcp(cp);
        int swz = (lr & 7) << 4;
        float pr = 0.f;
        #pragma unroll
        for (int j = 0; j < 2; ++j) {
            short8 u8 = *(const short8*)(Ur + j*8);
            short8 w8 = *(const short8*)(Wr + j*8);
            short8 xo;
            if (born_) {
                xo = u8;
                #pragma unroll
                for (int m = 0; m < 8; ++m)
                    pr += bf2f((unsigned short)w8[m]) * bf2f((unsigned short)u8[m]);
            } else {
                short8 v8 = *(const short8*)(Vr + j*8);
                #pragma unroll
                for (int m = 0; m < 8; ++m) {
                    float x = bf2f((unsigned short)u8[m])
                              * frcp(cp + bf2f((unsigned short)v8[m]) * icp);
                    xo[m] = (short)f2bf(x);
                    pr += bf2f((unsigned short)w8[m]) * x;
                }
            }
            *(short8*)(xb + ((lr*2048 + lane*32 + j*16) ^ swz)) = xo;
        }
        if (ot == 0) {   // dcp1 = w1.X1 (X1 identical across ot; one block stores)
            pr += __shfl_xor(pr, 1); pr += __shfl_xor(pr, 2); pr += __shfl_xor(pr, 4);
            pr += __shfl_xor(pr, 8); pr += __shfl_xor(pr, 16); pr += __shfl_xor(pr, 32);
            if (lane == 0) st_f32_sc(&DpA[sig*BB + row], pr);
        }
    };
    auto GEMM = [&](const char* xb, int L, bool storeX, int h, bool born_, int sig,
                    float* Dst) {
        f32x4 aa = {0.f,0.f,0.f,0.f}, ai = {0.f,0.f,0.f,0.f};
        const short8* pb = (const short8*)(Cact + (size_t)L*NN*NN + (size_t)brow*NN + kw*512) + g4;
        const short8* pc = (const short8*)(Cinh + (size_t)L*NN*NN + (size_t)brow*NN + kw*512) + g4;
        int abase = r16*2048 + kw*1024 + g4*16;
        int swz = (r16 & 7) << 4;
        if (born_) {
            #pragma unroll
            for (int s = 0; s < 16; ++s) {
                short8 av = *(const short8*)(xb + ((abase + s*64) ^ swz));
                aa = MFMA(av, pb[s*4], aa);
            }
        } else {
            #pragma unroll
            for (int s = 0; s < 16; ++s) {
                short8 av = *(const short8*)(xb + ((abase + s*64) ^ swz));
                aa = MFMA(av, pb[s*4], aa);
                ai = MFMA(av, pc[s*4], ai);
            }
        }
        if (kw != 0) {
            #pragma unroll
            for (int e = 0; e < 4; ++e) {
                redf[(oc*8 + e)*64 + lane]     = aa[e];
                redf[(oc*8 + 4 + e)*64 + lane] = ai[e];
            }
        }
        __syncthreads();
        if (kw == 0) {
            #pragma unroll
            for (int e = 0; e < 4; ++e) {
                aa[e] += redf[(oc*8 + e)*64 + lane];
                ai[e] += redf[(oc*8 + 4 + e)*64 + lane];
            }
            int ol = oc*16 + r16;
            float kdt = kdT_s[L][ol], kdi = kdI_s[L][ol], kk6 = k6_s[L][ol], wn = w_s[L+1][ol];
            #pragma unroll
            for (int r = 0; r < 4; ++r) {
                int slot = h*16 + g4*4 + r;
                float xn;
                if (born_) xn = aa[r] * frcp(kdt);
                else {
                    float cp = cp_s[slot];
                    xn = aa[r] * frcp(kdt*cp + kk6*ai[r]*frcp(kdi*cp));
                }
                if (storeX)
                    st_u16_sc(&X2[(size_t)(b0+slot)*NN + o0 + ol], f2bf(xn));
                float v = wn * xn;
                v += __shfl_xor(v, 1); v += __shfl_xor(v, 2);
                v += __shfl_xor(v, 4); v += __shfl_xor(v, 8);
                if (r16 == 0) dsum[oc][g4*4 + r] = v;
            }
        }
        __syncthreads();
        if (tid < 16) {   // per-block dcp partial -> one sc store per row (no RMW)
            float s = 0.f;
            #pragma unroll
            for (int o = 0; o < 8; ++o) s += dsum[o][tid];
            st_f32_sc(&Dst[(sig*8 + ot)*BB + b0 + h*16 + tid], s);
        }
    };
    auto STAGE = [&](int h, char* xb) {
        const char* src = (const char*)(X2 + (size_t)(b0 + h*16 + wid) * NN) + lane*16;
        i32x4 r2[2];
        ld2k_sc(src, r2);
        int base = wid*2048 + lane*16;
        int swz = (wid & 7) << 4;
        *(i32x4*)(xb + (base ^ swz)) = r2[0];
        *(i32x4*)(xb + ((base + 1024) ^ swz)) = r2[1];
    };

    char* xb0 = (char*)bufs[0];
    char* xb1 = (char*)bufs[1];

    for (int t = 0; t <= NSWEEP; ++t) {
        const bool born_ = (t == 0);
        const int sig = t & 1;
        // ---- step 1: H0 front (update + A + B-layer GEMM) ----
        bar_wait(L_d0, GRP*(t+1));
        if (!born_) UPDATE(0, t);
        __syncthreads();
        PHASE_A(0, xb0, born_, sig);
        __syncthreads();
        GEMM(xb0, 1, true, 0, born_, sig, DpB);
        bar_arrive(L_x0);
        // ---- step 2: H1 front ----
        bar_wait(L_d1, GRP*(t+1));
        if (!born_) UPDATE(1, t);
        __syncthreads();
        PHASE_A(1, xb1, born_, sig);
        __syncthreads();
        GEMM(xb1, 1, true, 1, born_, sig, DpB);
        bar_arrive(L_x1);
        // ---- step 3: H0 back (stage + C-layer GEMM) ----
        bar_wait(L_x0, GRP*(t+1));
        STAGE(0, xb0);
        __syncthreads();
        GEMM(xb0, 2, false, 0, born_, sig, DpC);
        bar_arrive(L_d0);
        // ---- step 4: H1 back ----
        bar_wait(L_x1, GRP*(t+1));
        STAGE(1, xb1);
        __syncthreads();
        GEMM(xb1, 2, false, 1, born_, sig, DpC);
        bar_arrive(L_d1);
    }
    // ---- finalize: one more bisection decision per half; out = 0.5*(lo+hi) = cp_s ----
    bar_wait(L_d0, GRP*(NSWEEP+2));
    UPDATE(0, NSWEEP+1);
    __syncthreads();
    bar_wait(L_d1, GRP*(NSWEEP+2));
    UPDATE(1, NSWEEP+1);
    __syncthreads();
    if (ot == 0 && tid < 32) out[b0 + tid] = cp_s[tid];
}

extern "C" void kernel_launch(void* const* d_in, const int* in_sizes, int n_in,
                              void* d_out, int out_size, void* d_ws, size_t ws_size,
                              hipStream_t stream) {
    const float* inputs = (const float*)d_in[0];
    const float* k1   = (const float*)d_in[1];
    const float* k1n  = (const float*)d_in[2];
    const float* k2   = (const float*)d_in[3];
    const float* k3   = (const float*)d_in[4];
    const float* k3n  = (const float*)d_in[5];
    const float* k4   = (const float*)d_in[6];
    const float* k6   = (const float*)d_in[7];
    const float* kdI  = (const float*)d_in[8];
    const float* kdT  = (const float*)d_in[9];
    const float* TA0  = (const float*)d_in[10];
    const float* TI0  = (const float*)d_in[11];
    const float* Ci0  = (const float*)d_in[12];
    const float* E0   = (const float*)d_in[13];
    const float* masks = (const float*)d_in[14];
    float* out = (float*)d_out;

    char* ws = (char*)d_ws;
    unsigned short* Cact = (unsigned short*)(ws + 0);            // 8 MB
    unsigned short* Cinh = (unsigned short*)(ws + 8388608);      // 8 MB
    unsigned short* U0b  = (unsigned short*)(ws + 16777216);     // 512 KB (bf16 U')
    unsigned short* V0b  = (unsigned short*)(ws + 17301504);     // 512 KB (bf16 V')
    unsigned short* X0   = (unsigned short*)(ws + 17825792);     // 512 KB
    unsigned short* X2   = (unsigned short*)(ws + 18350080);     // 512 KB
    float* w   = (float*)(ws + 18874368);                        // 16 KB
    int* bar   = (int*)(ws + 18890752);                          // 8 KB (8 groups x 1KB)
    float* DpA = (float*)(ws + 18898944);                        // 2 KB  [2][256]
    float* DpB = (float*)(ws + 18900992);                        // 16 KB [2][8][256]
    float* DpC = (float*)(ws + 18917376);                        // 16 KB [2][8][256]
    unsigned short* pw1b = (unsigned short*)(ws + 18933760);     // 2 KB bf16 w1

    // zero w + bar (contiguous); Dp buffers are written before first read
    hipMemsetAsync(ws + 18874368, 0, 16384 + 8192, stream);

    hipLaunchKernelGGL(prep_kernel, dim3(256), dim3(256), 0, stream,
                       k1, k1n, k2, k3, k3n, k4, TA0, TI0, Ci0, masks, E0, Cact, Cinh, w);
    hipLaunchKernelGGL(x0_kernel, dim3(256), dim3(256), 0, stream, inputs, X0, w, pw1b);

    void* args[] = { &inputs, &X0, &Cact, &Cinh, &U0b, &V0b, &X2,
                     &w, &DpA, &DpB, &DpC, &bar, &pw1b, &k6, &kdI, &kdT, &out };
    hipLaunchCooperativeKernel((const void*)solve_kernel, dim3(64), dim3(1024),
                               args, 0, stream);
}

// Round 11
// 450.188 us; speedup vs baseline: 2.0097x; 2.0097x over previous
//
#include <hip/hip_runtime.h>
#include <hip/hip_bf16.h>

#define NN 1024
#define BB 256
#define NSWEEP 10   // born + 10 bisections + finalize decision; bf16 term ~8 << 25.76

typedef __attribute__((ext_vector_type(8))) short short8;
typedef __attribute__((ext_vector_type(4))) float f32x4;
typedef __attribute__((ext_vector_type(4))) unsigned short u16x4;
typedef __attribute__((ext_vector_type(4))) int i32x4;

#define MFMA(a,b,c) __builtin_amdgcn_mfma_f32_16x16x32_bf16(a,b,c,0,0,0)

__device__ __forceinline__ unsigned short f2bf(float f) {
    union { float f; unsigned int i; } c; c.f = f;
    unsigned int x = c.i;
    return (unsigned short)((x + 0x7fffu + ((x >> 16) & 1u)) >> 16);
}
__device__ __forceinline__ float bf2f(unsigned short u) {
    union { unsigned int i; float f; } c; c.i = ((unsigned int)u) << 16; return c.f;
}
__device__ __forceinline__ float frcp(float x) { return __builtin_amdgcn_rcpf(x); }

// ---- coherent-point helpers (MALL; XCD L2s not cross-coherent) ----
__device__ __forceinline__ void st_u16_sc(unsigned short* p, unsigned short v) {
    asm volatile("global_store_short %0, %1, off sc0 sc1" :: "v"(p), "v"((unsigned)v) : "memory");
}
__device__ __forceinline__ void st_f32_sc(float* p, float v) {
    asm volatile("global_store_dword %0, %1, off sc0 sc1" :: "v"(p), "v"(v) : "memory");
}
__device__ __forceinline__ void st_i32_sc(int* p, int v) {
    asm volatile("global_store_dword %0, %1, off sc0 sc1" :: "v"(p), "v"(v) : "memory");
}
__device__ __forceinline__ float ld_f32_sc(const float* p) {
    float v;
    asm volatile("global_load_dword %0, %1, off sc0 sc1\n\ts_waitcnt vmcnt(0)"
                 : "=v"(v) : "v"(p) : "memory");
    return v;
}
__device__ __forceinline__ int ld_i32_sc(const int* p) {
    int v;
    asm volatile("global_load_dword %0, %1, off sc0 sc1\n\ts_waitcnt vmcnt(0)"
                 : "=v"(v) : "v"(p) : "memory");
    return v;
}
__device__ __forceinline__ void ld2_f32_sc(const float* p0, const float* p1, float& a, float& b) {
    asm volatile("global_load_dword %0, %2, off sc0 sc1\n\t"
                 "global_load_dword %1, %3, off sc0 sc1\n\t"
                 "s_waitcnt vmcnt(0)"
                 : "=&v"(a), "=&v"(b) : "v"(p0), "v"(p1) : "memory");
}
__device__ __forceinline__ void ld2k_sc(const char* p, i32x4* r) {
    asm volatile(
        "global_load_dwordx4 %0, %2, off sc0 sc1\n\t"
        "global_load_dwordx4 %1, %2, off offset:1024 sc0 sc1\n\t"
        "s_waitcnt vmcnt(0)"
        : "=&v"(r[0]), "=&v"(r[1]) : "v"(p) : "memory");
}

// ---- slot barrier: no RMW. Each block stores a round number into its own slot;
// waiter polls all 32 slots lane-parallel (one 128B line -> one MALL RT per poll).
__device__ __forceinline__ void bar_arrive(int* line, int slot, int val) {
    asm volatile("s_waitcnt vmcnt(0)" ::: "memory");   // data stores drained first
    __syncthreads();
    if (threadIdx.x == 0) st_i32_sc(&line[slot], val);
}
__device__ __forceinline__ void bar_wait(const int* line, int target) {
    if (threadIdx.x < 64) {
        int l = threadIdx.x;
        for (;;) {
            int v = (l < 32) ? ld_i32_sc(&line[l]) : target;
            if (__all(v >= target)) break;
            __builtin_amdgcn_s_sleep(1);
        }
    }
    __syncthreads();
}

// ---------------- precompute: Cact/Cinh (bf16) + w (col-sums) ----------------
__global__ __launch_bounds__(256) void prep_kernel(
    const float* __restrict__ k1, const float* __restrict__ k1n, const float* __restrict__ k2,
    const float* __restrict__ k3, const float* __restrict__ k3n, const float* __restrict__ k4,
    const float* __restrict__ TA0, const float* __restrict__ TI0, const float* __restrict__ Ci0,
    const float* __restrict__ masks, const float* __restrict__ E0p,
    unsigned short* __restrict__ Cact, unsigned short* __restrict__ Cinh, float* __restrict__ w)
{
    int bid = blockIdx.x;
    int l = bid >> 6;
    int rc = bid & 63;
    int t = threadIdx.x;
    float E0 = E0p[0];
    size_t base = (size_t)l * NN * NN + (size_t)rc * 16 * NN;
    int col0 = t * 4;
    float wsum0 = 0.f, wsum1 = 0.f, wsum2 = 0.f, wsum3 = 0.f;
    for (int r = 0; r < 16; ++r) {
        size_t idx = base + (size_t)r * NN + col0;
        f32x4 m  = *(const f32x4*)(masks + idx);
        f32x4 a1 = *(const f32x4*)(k1 + idx);
        f32x4 b1 = *(const f32x4*)(k1n + idx);
        f32x4 a2 = *(const f32x4*)(k2 + idx);
        f32x4 ta = *(const f32x4*)(TA0 + idx);
        f32x4 a3 = *(const f32x4*)(k3 + idx);
        f32x4 b3 = *(const f32x4*)(k3n + idx);
        f32x4 a4 = *(const f32x4*)(k4 + idx);
        f32x4 ti = *(const f32x4*)(TI0 + idx);
        f32x4 ci = *(const f32x4*)(Ci0 + idx);
        u16x4 oa, oi;
        float ws[4];
        #pragma unroll
        for (int j = 0; j < 4; ++j) {
            float ka = a1[j] * ta[j] * frcp(b1[j] + a2[j]);
            float ki = a3[j] * ti[j] * frcp(b3[j] + a4[j]);
            bool act = m[j] > 0.f, inh = m[j] < 0.f;
            oa[j] = f2bf(act ? a2[j] * ka * E0 : 0.f);
            oi[j] = f2bf(inh ? ci[j] : 0.f);
            ws[j] = (act ? ka : 0.f) + (inh ? ki : 0.f);
        }
        wsum0 += ws[0]; wsum1 += ws[1]; wsum2 += ws[2]; wsum3 += ws[3];
        *(u16x4*)(Cact + idx) = oa;
        *(u16x4*)(Cinh + idx) = oi;
    }
    atomicAdd(&w[l * NN + col0 + 0], wsum0);
    atomicAdd(&w[l * NN + col0 + 1], wsum1);
    atomicAdd(&w[l * NN + col0 + 2], wsum2);
    atomicAdd(&w[l * NN + col0 + 3], wsum3);
}

__global__ __launch_bounds__(256) void x0_kernel(const float* __restrict__ in,
                                                 unsigned short* __restrict__ o,
                                                 const float* __restrict__ w,
                                                 unsigned short* __restrict__ pw1b)
{
    int i = (blockIdx.x * 256 + threadIdx.x) * 4;
    f32x4 v = *(const f32x4*)(in + i);
    u16x4 r;
    #pragma unroll
    for (int j = 0; j < 4; ++j) r[j] = f2bf(v[j]);
    *(u16x4*)(o + i) = r;
    if (blockIdx.x < 4) {
        int p = blockIdx.x * 256 + threadIdx.x;
        pw1b[p] = f2bf(w[NN + p]);
    }
}

// ---------------- cooperative solve: round-6 structure, atomic-free exchange ----------------
// 256 blocks x 1024 threads (16 waves). Block tile: 32 samples (bt, 8 groups) x 32 outs (ot).
// Half-split pipeline (H0/H1). dcp partials: one plain sc store per (ot,row), no RMW,
// no resets; UPDATE gathers 32 partials/row lane-parallel (1 MALL RT) + LDS reduce.
__global__ __launch_bounds__(1024) void solve_kernel(
    const float* __restrict__ inputs,
    const unsigned short* __restrict__ X0,
    const unsigned short* __restrict__ Cact,
    const unsigned short* __restrict__ Cinh,
    unsigned short* __restrict__ U0b, unsigned short* __restrict__ V0b,
    unsigned short* __restrict__ X2,
    const float* __restrict__ w,
    float* __restrict__ DpA, float* __restrict__ DpB, float* __restrict__ DpC,
    int* __restrict__ bar, const unsigned short* __restrict__ pw1b,
    const float* __restrict__ k6, const float* __restrict__ kdI,
    const float* __restrict__ kdT, float* __restrict__ out)
{
    __shared__ unsigned short bufs[2][16][1024];      // 64KB: per-half X tile (XOR-swizzled)
    __shared__ float redf[7168];                      // 28KB: K-split reduction scratch
    __shared__ float dsum[2][16];                     // per-oc dcp partials
    __shared__ float gsum[32][16];                    // UPDATE gather scratch
    __shared__ float gA[16];
    __shared__ float lo_s[32], hi_s[32], cp_s[32], dcp0_s[32];
    __shared__ float w_s[4][32], kdT_s[4][32], kdI_s[4][32], k6_s[4][32];

    const int bid = blockIdx.x;
    const int ot = (bid & 7) * 4 + ((bid >> 3) & 3);  // same-ot -> same XCD (B L2-local)
    const int bt = bid >> 5;
    const int b0 = bt * 32, o0 = ot * 32;
    const int tid = threadIdx.x;
    const int wid = tid >> 6, lane = tid & 63;
    const int r16 = lane & 15, g4 = lane >> 4;
    // sweep-GEMM mapping: 2 out-subtiles (oc) x 8-way K-split (kw, K=128 each)
    const int oc = wid & 1, kw = wid >> 1;
    const int brow = o0 + oc * 16 + r16;
    // phase-0 mapping: 4 subtiles x 4-way K-split (K=256)
    const int sub0 = wid >> 2, kw0 = wid & 3;
    const int bh0 = sub0 >> 1, oc0 = sub0 & 1;
    const int k00 = kw0 * 256 + g4 * 8;
    const int arow0 = b0 + bh0 * 16 + r16;
    const int brow0 = o0 + oc0 * 16 + r16;

    int* L_x0 = bar + bt * 128;       // X2-ready, half 0 (32 slots)
    int* L_x1 = L_x0 + 32;            // X2-ready, half 1
    int* L_d0 = L_x0 + 64;            // D-ready, half 0 (also phase0->sweep0 gate)
    int* L_d1 = L_x0 + 96;            // D-ready, half 1

    // ---- init LDS params ----
    if (tid < 128) {
        int l = tid >> 5, c = tid & 31;
        w_s[l][c]   = w[l * NN + o0 + c];
        kdT_s[l][c] = kdT[l * NN + o0 + c];
        kdI_s[l][c] = kdI[l * NN + o0 + c];
        k6_s[l][c]  = k6[l * NN + o0 + c];
    }
    {   // dcp0 = w0 . x0  (fp32 exact)
        int row = tid >> 5, seg = tid & 31;
        const float* xr = inputs + (size_t)(b0 + row) * NN + seg * 32;
        const float* wr = w + seg * 32;
        float p = 0.f;
        #pragma unroll
        for (int kk = 0; kk < 32; ++kk) p += wr[kk] * xr[kk];
        p += __shfl_xor(p, 1); p += __shfl_xor(p, 2); p += __shfl_xor(p, 4);
        p += __shfl_xor(p, 8); p += __shfl_xor(p, 16);
        if (seg == 0) dcp0_s[row] = p;
    }

    // ---- phase 0: U' = (Cact0@X0)/kdT0, V' = (k60/kdI0)*(Cinh0@X0)/kdT0 (bf16, sc) ----
    {
        f32x4 aa = {0.f,0.f,0.f,0.f}, ai = {0.f,0.f,0.f,0.f};
        const short8* pa = (const short8*)(X0 + (size_t)arow0 * NN + k00);
        const short8* pb = (const short8*)(Cact + (size_t)brow0 * NN + k00);
        const short8* pc = (const short8*)(Cinh + (size_t)brow0 * NN + k00);
        #pragma unroll
        for (int s = 0; s < 8; ++s) {
            short8 av = pa[s * 4];
            aa = MFMA(av, pb[s * 4], aa);
            ai = MFMA(av, pc[s * 4], ai);
        }
        if (kw0 != 0) {
            #pragma unroll
            for (int e = 0; e < 4; ++e) {
                redf[((sub0*3 + kw0-1)*8 + e)*64 + lane]   = aa[e];
                redf[((sub0*3 + kw0-1)*8 + 4+e)*64 + lane] = ai[e];
            }
        }
        __syncthreads();
        if (kw0 == 0) {
            #pragma unroll
            for (int p = 0; p < 3; ++p)
                #pragma unroll
                for (int e = 0; e < 4; ++e) {
                    aa[e] += redf[((sub0*3 + p)*8 + e)*64 + lane];
                    ai[e] += redf[((sub0*3 + p)*8 + 4+e)*64 + lane];
                }
            int ol = oc0*16 + r16;
            float ia = frcp(kdT_s[0][ol]);
            float cc = k6_s[0][ol] * frcp(kdI_s[0][ol]);
            #pragma unroll
            for (int r = 0; r < 4; ++r) {
                size_t idx = (size_t)(b0 + bh0*16 + g4*4 + r) * NN + o0 + ol;
                st_u16_sc(&U0b[idx], f2bf(aa[r] * ia));
                st_u16_sc(&V0b[idx], f2bf(ai[r] * cc * ia));
            }
        }
    }
    // arrive on both D lines (phase0 -> sweep0 gate), val=1
    asm volatile("s_waitcnt vmcnt(0)" ::: "memory");
    __syncthreads();
    if (tid == 0) {
        st_i32_sc(&L_d0[ot], 1);
        st_i32_sc(&L_d1[ot], 1);
    }

    // ---- lambdas ----
    auto UPDATE = [&](int h, int t) {
        const int prevsig = (t - 1) & 1;
        if (tid < 512) {
            int o = tid >> 4, i = tid & 15;
            int row = b0 + h*16 + i;
            float vb, vc;
            ld2_f32_sc(&DpB[(prevsig*32 + o)*BB + row], &DpC[(prevsig*32 + o)*BB + row], vb, vc);
            gsum[o][i] = vb + vc;
        } else if (tid < 528) {
            int i = tid - 512;
            gA[i] = ld_f32_sc(&DpA[prevsig*BB + b0 + h*16 + i]);
        }
        __syncthreads();
        if (tid < 16) {
            int i = h*16 + tid;
            float S = gA[tid];
            #pragma unroll
            for (int o = 0; o < 32; ++o) S += gsum[o][tid];
            float G = 1.f + dcp0_s[i] + S;
            float lo, hi;
            if (t == 1) { lo = 1.f; hi = G; }
            else {
                lo = lo_s[i]; hi = hi_s[i];
                float mid = cp_s[i];
                if (G > mid) lo = mid; else hi = mid;
            }
            lo_s[i] = lo; hi_s[i] = hi;
            cp_s[i] = 0.5f * (lo + hi);
        }
    };
    auto PHASE_A = [&](int h, char* xb, bool born_, int sig) {
        int lr = wid;                              // one wave per sample row
        int row = b0 + h*16 + lr;
        const unsigned short* Ur = U0b + (size_t)row * NN + lane*16;
        const unsigned short* Vr = V0b + (size_t)row * NN + lane*16;
        const unsigned short* Wr = pw1b + lane*16;
        float cp = born_ ? 1.f : cp_s[h*16 + lr];
        float icp = frcp(cp);
        int swz = (lr & 7) << 4;
        float pr = 0.f;
        #pragma unroll
        for (int j = 0; j < 2; ++j) {
            short8 u8 = *(const short8*)(Ur + j*8);
            short8 w8 = *(const short8*)(Wr + j*8);
            short8 xo;
            if (born_) {
                xo = u8;
                #pragma unroll
                for (int m = 0; m < 8; ++m)
                    pr += bf2f((unsigned short)w8[m]) * bf2f((unsigned short)u8[m]);
            } else {
                short8 v8 = *(const short8*)(Vr + j*8);
                #pragma unroll
                for (int m = 0; m < 8; ++m) {
                    float x = bf2f((unsigned short)u8[m])
                              * frcp(cp + bf2f((unsigned short)v8[m]) * icp);
                    xo[m] = (short)f2bf(x);
                    pr += bf2f((unsigned short)w8[m]) * x;
                }
            }
            *(short8*)(xb + ((lr*2048 + lane*32 + j*16) ^ swz)) = xo;
        }
        if (ot == 0) {   // X1 identical across ot; one block stores dcp1
            pr += __shfl_xor(pr, 1); pr += __shfl_xor(pr, 2); pr += __shfl_xor(pr, 4);
            pr += __shfl_xor(pr, 8); pr += __shfl_xor(pr, 16); pr += __shfl_xor(pr, 32);
            if (lane == 0) st_f32_sc(&DpA[sig*BB + row], pr);
        }
    };
    auto GEMM = [&](const char* xb, int L, bool storeX, int h, bool born_, int sig,
                    float* Dst) {
        f32x4 aa = {0.f,0.f,0.f,0.f}, ai = {0.f,0.f,0.f,0.f};
        const short8* pb = (const short8*)(Cact + (size_t)L*NN*NN + (size_t)brow*NN + kw*128 + g4*8);
        const short8* pc = (const short8*)(Cinh + (size_t)L*NN*NN + (size_t)brow*NN + kw*128 + g4*8);
        int abase = r16*2048 + kw*256 + g4*16;
        int swz = (r16 & 7) << 4;
        if (born_) {
            #pragma unroll
            for (int s = 0; s < 4; ++s) {
                short8 av = *(const short8*)(xb + ((abase + s*64) ^ swz));
                aa = MFMA(av, pb[s*4], aa);
            }
        } else {
            #pragma unroll
            for (int s = 0; s < 4; ++s) {
                short8 av = *(const short8*)(xb + ((abase + s*64) ^ swz));
                aa = MFMA(av, pb[s*4], aa);
                ai = MFMA(av, pc[s*4], ai);
            }
        }
        if (kw != 0) {
            #pragma unroll
            for (int e = 0; e < 4; ++e) {
                redf[((oc*7 + kw-1)*8 + e)*64 + lane]   = aa[e];
                redf[((oc*7 + kw-1)*8 + 4+e)*64 + lane] = ai[e];
            }
        }
        __syncthreads();
        if (kw == 0) {
            #pragma unroll
            for (int q = 0; q < 7; ++q)
                #pragma unroll
                for (int e = 0; e < 4; ++e) {
                    aa[e] += redf[((oc*7 + q)*8 + e)*64 + lane];
                    ai[e] += redf[((oc*7 + q)*8 + 4+e)*64 + lane];
                }
            int ol = oc*16 + r16;
            float kdt = kdT_s[L][ol], kdi = kdI_s[L][ol], kk6 = k6_s[L][ol], wn = w_s[L+1][ol];
            #pragma unroll
            for (int r = 0; r < 4; ++r) {
                int slot = h*16 + g4*4 + r;
                float xn;
                if (born_) xn = aa[r] * frcp(kdt);
                else {
                    float cp = cp_s[slot];
                    xn = aa[r] * frcp(kdt*cp + kk6*ai[r]*frcp(kdi*cp));
                }
                if (storeX)
                    st_u16_sc(&X2[(size_t)(b0+slot)*NN + o0 + ol], f2bf(xn));
                float v = wn * xn;
                v += __shfl_xor(v, 1); v += __shfl_xor(v, 2);
                v += __shfl_xor(v, 4); v += __shfl_xor(v, 8);
                if (r16 == 0) dsum[oc][g4*4 + r] = v;
            }
        }
        __syncthreads();
        if (tid < 16) {   // per-block dcp partial: one plain store per row, no RMW
            float s = dsum[0][tid] + dsum[1][tid];
            st_f32_sc(&Dst[(sig*32 + ot)*BB + b0 + h*16 + tid], s);
        }
    };
    auto STAGE = [&](int h, char* xb) {
        const char* src = (const char*)(X2 + (size_t)(b0 + h*16 + wid) * NN) + lane*16;
        i32x4 r2[2];
        ld2k_sc(src, r2);
        int base = wid*2048 + lane*16;
        int swz = (wid & 7) << 4;
        *(i32x4*)(xb + (base ^ swz)) = r2[0];
        *(i32x4*)(xb + ((base + 1024) ^ swz)) = r2[1];
    };

    char* xb0 = (char*)bufs[0];
    char* xb1 = (char*)bufs[1];

    for (int t = 0; t <= NSWEEP; ++t) {
        const bool born_ = (t == 0);
        const int sig = t & 1;
        // ---- step 1: H0 front (update + A + layer-1 GEMM) ----
        bar_wait(L_d0, t + 1);
        if (!born_) UPDATE(0, t);
        __syncthreads();
        PHASE_A(0, xb0, born_, sig);
        __syncthreads();
        GEMM(xb0, 1, true, 0, born_, sig, DpB);
        bar_arrive(L_x0, ot, t + 1);
        // ---- step 2: H1 front ----
        bar_wait(L_d1, t + 1);
        if (!born_) UPDATE(1, t);
        __syncthreads();
        PHASE_A(1, xb1, born_, sig);
        __syncthreads();
        GEMM(xb1, 1, true, 1, born_, sig, DpB);
        bar_arrive(L_x1, ot, t + 1);
        // ---- step 3: H0 back (stage + layer-2 GEMM) ----
        bar_wait(L_x0, t + 1);
        STAGE(0, xb0);
        __syncthreads();
        GEMM(xb0, 2, false, 0, born_, sig, DpC);
        bar_arrive(L_d0, ot, t + 2);
        // ---- step 4: H1 back ----
        bar_wait(L_x1, t + 1);
        STAGE(1, xb1);
        __syncthreads();
        GEMM(xb1, 2, false, 1, born_, sig, DpC);
        bar_arrive(L_d1, ot, t + 2);
    }
    // ---- finalize: one more bisection decision per half; out = 0.5*(lo+hi) = cp_s ----
    bar_wait(L_d0, NSWEEP + 2);
    UPDATE(0, NSWEEP + 1);
    __syncthreads();
    bar_wait(L_d1, NSWEEP + 2);
    UPDATE(1, NSWEEP + 1);
    __syncthreads();
    if (ot == 0 && tid < 32) out[b0 + tid] = cp_s[tid];
}

extern "C" void kernel_launch(void* const* d_in, const int* in_sizes, int n_in,
                              void* d_out, int out_size, void* d_ws, size_t ws_size,
                              hipStream_t stream) {
    const float* inputs = (const float*)d_in[0];
    const float* k1   = (const float*)d_in[1];
    const float* k1n  = (const float*)d_in[2];
    const float* k2   = (const float*)d_in[3];
    const float* k3   = (const float*)d_in[4];
    const float* k3n  = (const float*)d_in[5];
    const float* k4   = (const float*)d_in[6];
    const float* k6   = (const float*)d_in[7];
    const float* kdI  = (const float*)d_in[8];
    const float* kdT  = (const float*)d_in[9];
    const float* TA0  = (const float*)d_in[10];
    const float* TI0  = (const float*)d_in[11];
    const float* Ci0  = (const float*)d_in[12];
    const float* E0   = (const float*)d_in[13];
    const float* masks = (const float*)d_in[14];
    float* out = (float*)d_out;

    char* ws = (char*)d_ws;
    unsigned short* Cact = (unsigned short*)(ws + 0);            // 8 MB
    unsigned short* Cinh = (unsigned short*)(ws + 8388608);      // 8 MB
    unsigned short* U0b  = (unsigned short*)(ws + 16777216);     // 512 KB (bf16 U')
    unsigned short* V0b  = (unsigned short*)(ws + 17301504);     // 512 KB (bf16 V')
    unsigned short* X0   = (unsigned short*)(ws + 17825792);     // 512 KB
    unsigned short* X2   = (unsigned short*)(ws + 18350080);     // 512 KB
    float* w   = (float*)(ws + 18874368);                        // 16 KB
    int* bar   = (int*)(ws + 18890752);                          // 4 KB (8 groups x 4 lines x 32 slots)
    float* DpA = (float*)(ws + 18894848);                        // 2 KB  [2][256]
    float* DpB = (float*)(ws + 18896896);                        // 64 KB [2][32][256]
    float* DpC = (float*)(ws + 18962432);                        // 64 KB [2][32][256]
    unsigned short* pw1b = (unsigned short*)(ws + 19027968);     // 2 KB bf16 w1

    // zero w + bar (contiguous); Dp buffers are written before first read
    hipMemsetAsync(ws + 18874368, 0, 16384 + 4096, stream);

    hipLaunchKernelGGL(prep_kernel, dim3(256), dim3(256), 0, stream,
                       k1, k1n, k2, k3, k3n, k4, TA0, TI0, Ci0, masks, E0, Cact, Cinh, w);
    hipLaunchKernelGGL(x0_kernel, dim3(256), dim3(256), 0, stream, inputs, X0, w, pw1b);

    void* args[] = { &inputs, &X0, &Cact, &Cinh, &U0b, &V0b, &X2,
                     &w, &DpA, &DpB, &DpC, &bar, &pw1b, &k6, &kdI, &kdT, &out };
    hipLaunchCooperativeKernel((const void*)solve_kernel, dim3(256), dim3(1024),
                               args, 0, stream);
}